// Round 3
// baseline (601.703 us; speedup 1.0000x reference)
//
#include <hip/hip_runtime.h>
#include <stdint.h>

// Binarized 5-layer MLP, B=32768, dims 784->256->256->256->256->10.
// Round 13: fused cooperative kernel with CUSTOM grid barrier.
// Round-12 evidence: fused+cg::grid.sync = 424us, VALUBusy 8.6% (~36us of
// real VALU work), FETCH 53MB (~15us) => ~360us of stall across 6 grid.syncs
// (~60us each: ROCm's sync does full L2 wb+inv per XCD + coarse s_sleep poll).
// Fix: minimal sense/generation barrier (agent-scope atomics, s_sleep(2) poll,
// per-wave acquire fence). Our dataflow keeps all cross-block data in
// device-scope atomics (stats) or read-only (x, packed weights from a prior
// regular launch), so the barrier's cache ops are nearly free.
//   prep launch: pack weights + zero stats + zero barrier (kernel boundary
//   makes them visible everywhere). fused: 5 barriers (after stats0..stats4).
// Math (verified R12, absmax 0.00195): d = popcount(a XOR w);
// binarize(BN(h)) == (A*d + C >= 0), A = -2*g*s, C = 2*g*s*mean_d + b,
// s = rsqrt(4*(E[d^2]-E[d]^2)+eps). Stats = exact integer sums in 16
// replicated atomic slots; consumers reduce replicas.

typedef unsigned long long u64;

#define NREP 16
#define GRID_BLOCKS 512

// ---- workspace layout (bytes) ----
#define OFF_WB0   0u          // u64 [16][256] = 32768 (words 0..12 used)
#define OFF_WB1   32768u      // u64 [4][256] = 8192
#define OFF_WB2   40960u
#define OFF_WB3   49152u
#define OFF_WB4   57344u      // u64 [4][16] = 512 (10 cols used)
#define OFF_SUMD  57856u      // int32 [16][5][256] = 81920
#define OFF_SUMDD 139776u     // u64   [16][5][256] = 163840
#define OFF_BAR   303616u     // unsigned [4]: {arrive_cnt, generation}
#define STATS_INT4 15360      // (81920+163840)/16
// fallback-only buffers
#define OFF_A1    (1u<<20)    // u64 [32768][4] = 1 MiB each
#define OFF_A2    (2u<<20)
#define OFF_A3    (3u<<20)
#define OFF_A4    (4u<<20)
#define OFF_H0    (5u<<20)    // short [32768][256] = 16 MiB

// 784-elem row -> 13 packed u64 words (consistent permuted bit order).
__device__ __forceinline__ u64 pack784_sel(const float* __restrict__ src,
                                           float thr, int lane) {
  u64 w[13];
  const float4* s4 = (const float4*)src;
#pragma unroll
  for (int j = 0; j < 3; ++j) {
    float4 v = s4[j * 64 + lane];
    w[4*j+0] = __ballot(v.x >= thr);
    w[4*j+1] = __ballot(v.y >= thr);
    w[4*j+2] = __ballot(v.z >= thr);
    w[4*j+3] = __ballot(v.w >= thr);
  }
  float4 v = make_float4(-1.f, -1.f, -1.f, -1.f);
  if (lane < 4) v = s4[192 + lane];
  u64 m0 = __ballot(v.x >= thr) & 0xFull;
  u64 m1 = __ballot(v.y >= thr) & 0xFull;
  u64 m2 = __ballot(v.z >= thr) & 0xFull;
  u64 m3 = __ballot(v.w >= thr) & 0xFull;
  w[12] = m0 | (m1 << 4) | (m2 << 8) | (m3 << 12);
  u64 sel = 0;
#pragma unroll
  for (int i = 0; i < 13; ++i) sel = (lane == i) ? w[i] : sel;
  return sel;
}

// 256-elem row -> 4 packed u64 words; bit l of word j <-> element 64*j+l.
__device__ __forceinline__ u64 pack256_sel(const float* __restrict__ src, int lane) {
  u64 w[4];
#pragma unroll
  for (int j = 0; j < 4; ++j) w[j] = __ballot(src[j * 64 + lane] >= 0.0f);
  u64 sel = 0;
#pragma unroll
  for (int i = 0; i < 4; ++i) sel = (lane == i) ? w[i] : sel;
  return sel;
}

// Reduce the 16 stats replicas for (layer, col); gs = g*rsqrt(var+eps), mean_d.
__device__ __forceinline__ void bn_gs_md(const int* __restrict__ sumd_rep,
                                         const u64* __restrict__ sumdd_rep,
                                         int layer, int col,
                                         const float* __restrict__ g,
                                         float& gs, float& md_out) {
  long long sd = 0; u64 sdd = 0;
#pragma unroll
  for (int r = 0; r < NREP; ++r) {
    sd  += sumd_rep [(r * 5 + layer) * 256 + col];
    sdd += sumdd_rep[(r * 5 + layer) * 256 + col];
  }
  double md  = (double)sd  * (1.0 / 32768.0);
  double mdd = (double)sdd * (1.0 / 32768.0);
  float var = (float)(4.0 * (mdd - md * md));
  float s   = rsqrtf(var + 1e-5f);
  gs = g[col] * s;
  md_out = (float)md;
}

#define DPK_SET(r, d) do { if ((r) & 1) dpk[(r) >> 1] |= ((unsigned)(d)) << 16; \
                           else dpk[(r) >> 1] = (unsigned)(d); } while (0)
#define DPK_GET(r) ((int)((dpk[(r) >> 1] >> (((r) & 1) * 16)) & 0xFFFFu))

// ---- custom grid barrier (generation counter, agent-scope atomics) ----
// Prior cross-block writes are device-scope atomicAdds (coherent at L3);
// __syncthreads drains all waves' VMEM before tid0 arrives. Releaser resets
// the counter BEFORE bumping gen (release), so next-barrier arrivals from
// fast blocks are safe (they acquire gen first). Consumers re-fence acquire
// per-wave so post-barrier plain loads can't hit stale L1/L2 lines.
__device__ __forceinline__ void grid_barrier(unsigned* bar, unsigned target) {
  __syncthreads();
  if (threadIdx.x == 0) {
    __builtin_amdgcn_fence(__ATOMIC_RELEASE, "agent");
    unsigned arrived = __hip_atomic_fetch_add(&bar[0], 1u, __ATOMIC_RELAXED,
                                              __HIP_MEMORY_SCOPE_AGENT) + 1u;
    if (arrived == (unsigned)GRID_BLOCKS) {
      __hip_atomic_store(&bar[0], 0u, __ATOMIC_RELAXED, __HIP_MEMORY_SCOPE_AGENT);
      __hip_atomic_store(&bar[1], target, __ATOMIC_RELEASE, __HIP_MEMORY_SCOPE_AGENT);
    } else {
      while (__hip_atomic_load(&bar[1], __ATOMIC_ACQUIRE,
                               __HIP_MEMORY_SCOPE_AGENT) < target) {
        __builtin_amdgcn_s_sleep(2);
      }
    }
  }
  __syncthreads();
  __builtin_amdgcn_fence(__ATOMIC_ACQUIRE, "agent");
}

// ================= prep: pack weights + zero stats + zero barrier =================
__global__ __launch_bounds__(256) void pack_weights(
    const float* __restrict__ W0, const float* __restrict__ W1,
    const float* __restrict__ W2, const float* __restrict__ W3,
    const float* __restrict__ W4,
    u64* __restrict__ wb0, u64* __restrict__ wb1, u64* __restrict__ wb2,
    u64* __restrict__ wb3, u64* __restrict__ wb4, int4* __restrict__ statsZ,
    unsigned* __restrict__ bar) {
  const int b = blockIdx.x, tid = threadIdx.x;
  const int lane = tid & 63, wave = tid >> 6;
  int gid = b * 256 + tid;
  if (gid < STATS_INT4) statsZ[gid] = make_int4(0, 0, 0, 0);
  if (b == 0 && tid < 4) bar[tid] = 0u;
  if (b < 64) {
    int row = b * 4 + wave;
    u64 sel = pack784_sel(W0 + (size_t)row * 784, 0.0f, lane);
    if (lane < 13) wb0[lane * 256 + row] = sel;
  } else if (b < 128) {
    int row = (b - 64) * 4 + wave;
    u64 sel = pack256_sel(W1 + (size_t)row * 256, lane);
    if (lane < 4) wb1[lane * 256 + row] = sel;
  } else if (b < 192) {
    int row = (b - 128) * 4 + wave;
    u64 sel = pack256_sel(W2 + (size_t)row * 256, lane);
    if (lane < 4) wb2[lane * 256 + row] = sel;
  } else if (b < 256) {
    int row = (b - 192) * 4 + wave;
    u64 sel = pack256_sel(W3 + (size_t)row * 256, lane);
    if (lane < 4) wb3[lane * 256 + row] = sel;
  } else {
    for (int row = wave; row < 10; row += 4) {
      u64 sel = pack256_sel(W4 + (size_t)row * 256, lane);
      if (lane < 4) wb4[lane * 16 + row] = sel;
    }
  }
}

// ================= fused cooperative kernel (custom barriers) =================
__global__ __launch_bounds__(256, 3) void fused_bnn(
    const float* __restrict__ x,
    const float* __restrict__ g0, const float* __restrict__ g1,
    const float* __restrict__ g2, const float* __restrict__ g3,
    const float* __restrict__ g4,
    const float* __restrict__ bb0, const float* __restrict__ bb1,
    const float* __restrict__ bb2, const float* __restrict__ bb3,
    const float* __restrict__ bb4,
    float* __restrict__ out, char* __restrict__ ws) {
  u64* wb0 = (u64*)(ws + OFF_WB0);
  u64* wb1 = (u64*)(ws + OFF_WB1);
  u64* wb2 = (u64*)(ws + OFF_WB2);
  u64* wb3 = (u64*)(ws + OFF_WB3);
  u64* wb4 = (u64*)(ws + OFF_WB4);
  int* sumd  = (int*)(ws + OFF_SUMD);
  u64* sumdd = (u64*)(ws + OFF_SUMDD);
  unsigned* bar = (unsigned*)(ws + OFF_BAR);

  const int b = blockIdx.x, tid = threadIdx.x;
  const int lane = tid & 63, wave = tid >> 6;
  const int row0 = b * 64;            // this block owns rows row0..row0+63
  const int rep = b & (NREP - 1);

  __shared__ u64 aw[64 * 16];         // 8 KB: layer-0 packed rows (13/16 words)
  __shared__ u64 bits[64 * 4];        // 2 KB: current activation bits
  __shared__ float sY[640];           // 2.5 KB: layer-4 pre-softmax

  unsigned dpk[32];                   // 64 d-values, 2x16b packed, registers

  // ---- P1: layer 0 — pack 64 x-rows into LDS, d0 -> dpk, stats0
  {
    u64 w0  = wb0[ 0 * 256 + tid], w1  = wb0[ 1 * 256 + tid];
    u64 w2  = wb0[ 2 * 256 + tid], w3  = wb0[ 3 * 256 + tid];
    u64 w4  = wb0[ 4 * 256 + tid], w5  = wb0[ 5 * 256 + tid];
    u64 w6  = wb0[ 6 * 256 + tid], w7  = wb0[ 7 * 256 + tid];
    u64 w8  = wb0[ 8 * 256 + tid], w9  = wb0[ 9 * 256 + tid];
    u64 w10 = wb0[10 * 256 + tid], w11 = wb0[11 * 256 + tid];
    u64 w12 = wb0[12 * 256 + tid];
    const float* base = x + (size_t)(row0 + wave * 16) * 784;  // 16 rows/wave
#pragma unroll 2
    for (int it = 0; it < 16; ++it) {
      u64 sel = pack784_sel(base + (size_t)it * 784, 0.5f, lane);
      if (lane < 13) aw[(wave * 16 + it) * 16 + lane] = sel;   // words 13..15 never read
    }
    __syncthreads();
    int sd = 0; unsigned sdd = 0;   // 64*784^2 = 39.3M fits u32
#pragma unroll
    for (int r = 0; r < 64; ++r) {
      const u64* ap = &aw[r * 16];
      int d = __popcll(ap[0] ^ w0)   + __popcll(ap[1] ^ w1)
            + __popcll(ap[2] ^ w2)   + __popcll(ap[3] ^ w3)
            + __popcll(ap[4] ^ w4)   + __popcll(ap[5] ^ w5)
            + __popcll(ap[6] ^ w6)   + __popcll(ap[7] ^ w7)
            + __popcll(ap[8] ^ w8)   + __popcll(ap[9] ^ w9)
            + __popcll(ap[10] ^ w10) + __popcll(ap[11] ^ w11)
            + __popcll(ap[12] ^ w12);
      DPK_SET(r, d);
      sd += d; sdd += (unsigned)(d * d);
    }
    atomicAdd(&sumd [(rep * 5 + 0) * 256 + tid], sd);
    atomicAdd(&sumdd[(rep * 5 + 0) * 256 + tid], (u64)sdd);
  }
  grid_barrier(bar, 1);

  // ---- P2..P4: layers 1..3 — binarize dpk -> bits -> new dpk + next stats
#pragma unroll
  for (int k = 0; k < 3; ++k) {
    const float* gk  = (k == 0) ? g0  : (k == 1) ? g1  : g2;
    const float* bk  = (k == 0) ? bb0 : (k == 1) ? bb1 : bb2;
    const u64*   wbN = (k == 0) ? wb1 : (k == 1) ? wb2 : wb3;
    float gs, md;
    bn_gs_md(sumd, sumdd, k, tid, gk, gs, md);
    const float A = -2.0f * gs;
    const float C = fmaf(gs, 2.0f * md, bk[tid]);
#pragma unroll
    for (int r = 0; r < 64; ++r) {
      bool bit = fmaf(A, (float)DPK_GET(r), C) >= 0.0f;
      u64 m = __ballot(bit);
      if (lane == 0) bits[r * 4 + wave] = m;
    }
    __syncthreads();
    u64 wn0 = wbN[0 * 256 + tid], wn1 = wbN[1 * 256 + tid];
    u64 wn2 = wbN[2 * 256 + tid], wn3 = wbN[3 * 256 + tid];
    int sd = 0; unsigned sdd = 0;   // 64 * 256^2 = 4.2M fits u32
#pragma unroll
    for (int r = 0; r < 64; ++r) {
      int d = __popcll(bits[r*4+0] ^ wn0) + __popcll(bits[r*4+1] ^ wn1)
            + __popcll(bits[r*4+2] ^ wn2) + __popcll(bits[r*4+3] ^ wn3);
      DPK_SET(r, d);
      sd += d; sdd += (unsigned)(d * d);
    }
    atomicAdd(&sumd [(rep * 5 + k + 1) * 256 + tid], sd);
    atomicAdd(&sumdd[(rep * 5 + k + 1) * 256 + tid], (u64)sdd);
    grid_barrier(bar, 2 + k);
  }

  // ---- P5: layer 4 — binarize d3 -> bits -> d4 (10 cols, in dpk of tid<10)
  {
    float gs, md;
    bn_gs_md(sumd, sumdd, 3, tid, g3, gs, md);
    const float A = -2.0f * gs;
    const float C = fmaf(gs, 2.0f * md, bb3[tid]);
#pragma unroll
    for (int r = 0; r < 64; ++r) {
      bool bit = fmaf(A, (float)DPK_GET(r), C) >= 0.0f;
      u64 m = __ballot(bit);
      if (lane == 0) bits[r * 4 + wave] = m;
    }
    __syncthreads();
    if (tid < 10) {
      u64 wn0 = wb4[0 * 16 + tid], wn1 = wb4[1 * 16 + tid];
      u64 wn2 = wb4[2 * 16 + tid], wn3 = wb4[3 * 16 + tid];
      int sd = 0; unsigned sdd = 0;
#pragma unroll
      for (int r = 0; r < 64; ++r) {
        int d = __popcll(bits[r*4+0] ^ wn0) + __popcll(bits[r*4+1] ^ wn1)
              + __popcll(bits[r*4+2] ^ wn2) + __popcll(bits[r*4+3] ^ wn3);
        DPK_SET(r, d);
        sd += d; sdd += (unsigned)(d * d);
      }
      atomicAdd(&sumd [(rep * 5 + 4) * 256 + tid], sd);
      atomicAdd(&sumdd[(rep * 5 + 4) * 256 + tid], (u64)sdd);
    }
  }
  grid_barrier(bar, 5);

  // ---- P6: BN4 + softmax + store
  {
    if (tid < 10) {
      float gs, md;
      bn_gs_md(sumd, sumdd, 4, tid, g4, gs, md);
      const float A = -2.0f * gs;
      const float C = fmaf(gs, 2.0f * md, bb4[tid]);
#pragma unroll
      for (int r = 0; r < 64; ++r)
        sY[r * 10 + tid] = fmaf(A, (float)DPK_GET(r), C);
    }
    __syncthreads();
    if (tid < 64) {
      float y[10]; float mx = -1e30f;
#pragma unroll
      for (int c = 0; c < 10; ++c) { y[c] = sY[tid * 10 + c]; mx = fmaxf(mx, y[c]); }
      float sum = 0.0f;
#pragma unroll
      for (int c = 0; c < 10; ++c) { y[c] = __expf(y[c] - mx); sum += y[c]; }
      float inv = 1.0f / sum;
      float* op = out + (size_t)(row0 + tid) * 10;
#pragma unroll
      for (int c = 0; c < 10; ++c) op[c] = y[c] * inv;
    }
  }
}

// ================= fallback: proven 7-dispatch pipeline (255us) =================
__global__ __launch_bounds__(256, 3) void mm0_kernel(
    const float* __restrict__ x, const u64* __restrict__ wb0T,
    short* __restrict__ h0, int* __restrict__ sumd_rep, u64* __restrict__ sumdd_rep) {
  const int b = blockIdx.x, tid = threadIdx.x;
  const int lane = tid & 63, wave = tid >> 6;
  const int row0 = b * 16;
  __shared__ u64 a0T[16 * 16];
  u64 w0  = wb0T[ 0 * 256 + tid], w1  = wb0T[ 1 * 256 + tid];
  u64 w2  = wb0T[ 2 * 256 + tid], w3  = wb0T[ 3 * 256 + tid];
  u64 w4  = wb0T[ 4 * 256 + tid], w5  = wb0T[ 5 * 256 + tid];
  u64 w6  = wb0T[ 6 * 256 + tid], w7  = wb0T[ 7 * 256 + tid];
  u64 w8  = wb0T[ 8 * 256 + tid], w9  = wb0T[ 9 * 256 + tid];
  u64 w10 = wb0T[10 * 256 + tid], w11 = wb0T[11 * 256 + tid];
  u64 w12 = wb0T[12 * 256 + tid];
  {
    const float* base = x + (size_t)(row0 + wave * 4) * 784;
#pragma unroll
    for (int it = 0; it < 4; ++it) {
      u64 sel = pack784_sel(base + (size_t)it * 784, 0.5f, lane);
      if (lane < 16) a0T[(wave * 4 + it) * 16 + lane] = sel;
    }
  }
  __syncthreads();
  int sd = 0; unsigned sdd = 0;
#pragma unroll 4
  for (int r = 0; r < 16; ++r) {
    const u64* ap = &a0T[r * 16];
    int d = __popcll(ap[0] ^ w0)   + __popcll(ap[1] ^ w1)
          + __popcll(ap[2] ^ w2)   + __popcll(ap[3] ^ w3)
          + __popcll(ap[4] ^ w4)   + __popcll(ap[5] ^ w5)
          + __popcll(ap[6] ^ w6)   + __popcll(ap[7] ^ w7)
          + __popcll(ap[8] ^ w8)   + __popcll(ap[9] ^ w9)
          + __popcll(ap[10] ^ w10) + __popcll(ap[11] ^ w11)
          + __popcll(ap[12] ^ w12);
    h0[(size_t)(row0 + r) * 256 + tid] = (short)(784 - 2 * d);
    sd += d; sdd += (unsigned)(d * d);
  }
  const int rep = b & (NREP - 1);
  atomicAdd(&sumd_rep [(rep * 5 + 0) * 256 + tid], sd);
  atomicAdd(&sumdd_rep[(rep * 5 + 0) * 256 + tid], (u64)sdd);
}

__global__ __launch_bounds__(256, 4) void b0_kernel(
    const short* __restrict__ h0,
    int* __restrict__ sumd_rep, u64* __restrict__ sumdd_rep,
    const float* __restrict__ g0, const float* __restrict__ bb0,
    u64* __restrict__ a1, const u64* __restrict__ wb1T) {
  const int b = blockIdx.x, tid = threadIdx.x;
  const int lane = tid & 63, wave = tid >> 6;
  const int row0 = b * 32;
  float gs, md;
  bn_gs_md(sumd_rep, sumdd_rep, 0, tid, g0, gs, md);
  const float mh = 784.0f - 2.0f * md;
  const float bb = bb0[tid];
  u64 wn0 = wb1T[0 * 256 + tid], wn1 = wb1T[1 * 256 + tid];
  u64 wn2 = wb1T[2 * 256 + tid], wn3 = wb1T[3 * 256 + tid];
  __shared__ u64 bits[32 * 4];
#pragma unroll 8
  for (int r = 0; r < 32; ++r) {
    float hv = (float)h0[(size_t)(row0 + r) * 256 + tid];
    bool bit = fmaf(gs, hv - mh, bb) >= 0.0f;
    u64 m = __ballot(bit);
    if (lane == 0) bits[r * 4 + wave] = m;
  }
  __syncthreads();
  if (tid < 128) a1[(size_t)row0 * 4 + tid] = bits[tid];
  int sd = 0; unsigned sdd = 0;
#pragma unroll 8
  for (int r = 0; r < 32; ++r) {
    int d = __popcll(bits[r*4+0] ^ wn0) + __popcll(bits[r*4+1] ^ wn1)
          + __popcll(bits[r*4+2] ^ wn2) + __popcll(bits[r*4+3] ^ wn3);
    sd += d; sdd += (unsigned)(d * d);
  }
  const int rep = b & (NREP - 1);
  atomicAdd(&sumd_rep [(rep * 5 + 1) * 256 + tid], sd);
  atomicAdd(&sumdd_rep[(rep * 5 + 1) * 256 + tid], (u64)sdd);
}

template<int LAYER, int NNEXT, int NSTRIDE>
__global__ __launch_bounds__(256, 4) void bmid_kernel(
    const u64* __restrict__ aK, const u64* __restrict__ wbKT,
    int* __restrict__ sumd_rep, u64* __restrict__ sumdd_rep,
    const float* __restrict__ gK, const float* __restrict__ bK,
    u64* __restrict__ aN, const u64* __restrict__ wbNT) {
  const int b = blockIdx.x, tid = threadIdx.x;
  const int lane = tid & 63, wave = tid >> 6;
  const int row0 = b * 32;
  __shared__ u64 ain[32 * 4];
  __shared__ u64 bits[32 * 4];
  if (tid < 128) ain[tid] = aK[(size_t)row0 * 4 + tid];
  float gs, md;
  bn_gs_md(sumd_rep, sumdd_rep, LAYER, tid, gK, gs, md);
  const float A = -2.0f * gs;
  const float C = fmaf(gs, 2.0f * md, bK[tid]);
  u64 wk0 = wbKT[0 * 256 + tid], wk1 = wbKT[1 * 256 + tid];
  u64 wk2 = wbKT[2 * 256 + tid], wk3 = wbKT[3 * 256 + tid];
  __syncthreads();
#pragma unroll 8
  for (int r = 0; r < 32; ++r) {
    int d = __popcll(ain[r*4+0] ^ wk0) + __popcll(ain[r*4+1] ^ wk1)
          + __popcll(ain[r*4+2] ^ wk2) + __popcll(ain[r*4+3] ^ wk3);
    bool bit = fmaf(A, (float)d, C) >= 0.0f;
    u64 m = __ballot(bit);
    if (lane == 0) bits[r * 4 + wave] = m;
  }
  __syncthreads();
  if (tid < 128) aN[(size_t)row0 * 4 + tid] = bits[tid];
  if (tid < NNEXT) {
    u64 wn0 = wbNT[0 * NSTRIDE + tid], wn1 = wbNT[1 * NSTRIDE + tid];
    u64 wn2 = wbNT[2 * NSTRIDE + tid], wn3 = wbNT[3 * NSTRIDE + tid];
    int sd = 0; unsigned sdd = 0;
#pragma unroll 8
    for (int r = 0; r < 32; ++r) {
      int d = __popcll(bits[r*4+0] ^ wn0) + __popcll(bits[r*4+1] ^ wn1)
            + __popcll(bits[r*4+2] ^ wn2) + __popcll(bits[r*4+3] ^ wn3);
      sd += d; sdd += (unsigned)(d * d);
    }
    const int rep = b & (NREP - 1);
    atomicAdd(&sumd_rep [(rep * 5 + LAYER + 1) * 256 + tid], sd);
    atomicAdd(&sumdd_rep[(rep * 5 + LAYER + 1) * 256 + tid], (u64)sdd);
  }
}

__global__ __launch_bounds__(256) void b4_kernel(
    const u64* __restrict__ a4, const u64* __restrict__ wb4T,
    const int* __restrict__ sumd_rep, const u64* __restrict__ sumdd_rep,
    const float* __restrict__ g4, const float* __restrict__ bb4,
    float* __restrict__ out) {
  __shared__ float sA[10], sC[10];
  __shared__ u64 w4s[40];
  const int tid = threadIdx.x;
  if (tid < 40) w4s[tid] = wb4T[(tid & 3) * 16 + (tid >> 2)];
  if (tid < 10) {
    float gs, md;
    bn_gs_md(sumd_rep, sumdd_rep, 4, tid, g4, gs, md);
    sA[tid] = -2.0f * gs;
    sC[tid] = fmaf(gs, 2.0f * md, bb4[tid]);
  }
  __syncthreads();
  const int row = blockIdx.x * 256 + tid;
  u64 a[4];
#pragma unroll
  for (int i = 0; i < 4; ++i) a[i] = a4[(size_t)row * 4 + i];
  float y[10];
  float mx = -1e30f;
#pragma unroll
  for (int c = 0; c < 10; ++c) {
    int d = __popcll(a[0] ^ w4s[c*4+0]) + __popcll(a[1] ^ w4s[c*4+1])
          + __popcll(a[2] ^ w4s[c*4+2]) + __popcll(a[3] ^ w4s[c*4+3]);
    y[c] = fmaf(sA[c], (float)d, sC[c]);
    mx = fmaxf(mx, y[c]);
  }
  float sum = 0.0f;
#pragma unroll
  for (int c = 0; c < 10; ++c) { y[c] = __expf(y[c] - mx); sum += y[c]; }
  float inv = 1.0f / sum;
#pragma unroll
  for (int c = 0; c < 10; ++c) out[(size_t)row * 10 + c] = y[c] * inv;
}

// ---------------- host ----------------
extern "C" void kernel_launch(void* const* d_in, const int* in_sizes, int n_in,
                              void* d_out, int out_size, void* d_ws, size_t ws_size,
                              hipStream_t stream) {
  (void)in_sizes; (void)n_in; (void)out_size; (void)ws_size;
  const float* x   = (const float*)d_in[0];
  const float* W0  = (const float*)d_in[1];
  const float* g0  = (const float*)d_in[2];
  const float* bb0 = (const float*)d_in[3];
  const float* W1  = (const float*)d_in[4];
  const float* g1  = (const float*)d_in[5];
  const float* bb1 = (const float*)d_in[6];
  const float* W2  = (const float*)d_in[7];
  const float* g2  = (const float*)d_in[8];
  const float* bb2 = (const float*)d_in[9];
  const float* W3  = (const float*)d_in[10];
  const float* g3  = (const float*)d_in[11];
  const float* bb3 = (const float*)d_in[12];
  const float* W4  = (const float*)d_in[13];
  const float* g4  = (const float*)d_in[14];
  const float* bb4 = (const float*)d_in[15];
  float* outp = (float*)d_out;
  char* ws = (char*)d_ws;

  u64*   wb0 = (u64*)(ws + OFF_WB0);
  u64*   wb1 = (u64*)(ws + OFF_WB1);
  u64*   wb2 = (u64*)(ws + OFF_WB2);
  u64*   wb3 = (u64*)(ws + OFF_WB3);
  u64*   wb4 = (u64*)(ws + OFF_WB4);
  int*   sumd  = (int*)(ws + OFF_SUMD);
  u64*   sumdd = (u64*)(ws + OFF_SUMDD);
  unsigned* bar = (unsigned*)(ws + OFF_BAR);

  pack_weights<<<257, 256, 0, stream>>>(W0, W1, W2, W3, W4,
                                        wb0, wb1, wb2, wb3, wb4,
                                        (int4*)(ws + OFF_SUMD), bar);

  void* args[] = { &x,
                   &g0, &g1, &g2, &g3, &g4,
                   &bb0, &bb1, &bb2, &bb3, &bb4,
                   &outp, &ws };
  hipError_t err = hipLaunchCooperativeKernel((const void*)fused_bnn,
                                              dim3(GRID_BLOCKS), dim3(256),
                                              args, 0, stream);
  if (err != hipSuccess) {
    (void)hipGetLastError();  // clear sticky error; run proven pipeline
    u64*   a1 = (u64*)(ws + OFF_A1);
    u64*   a2 = (u64*)(ws + OFF_A2);
    u64*   a3 = (u64*)(ws + OFF_A3);
    u64*   a4 = (u64*)(ws + OFF_A4);
    short* h0 = (short*)(ws + OFF_H0);
    mm0_kernel<<<2048, 256, 0, stream>>>(x, wb0, h0, sumd, sumdd);
    b0_kernel<<<1024, 256, 0, stream>>>(h0, sumd, sumdd, g0, bb0, a1, wb1);
    bmid_kernel<1, 256, 256><<<1024, 256, 0, stream>>>(a1, wb1, sumd, sumdd, g1, bb1, a2, wb2);
    bmid_kernel<2, 256, 256><<<1024, 256, 0, stream>>>(a2, wb2, sumd, sumdd, g2, bb2, a3, wb3);
    bmid_kernel<3, 10, 16><<<1024, 256, 0, stream>>>(a3, wb3, sumd, sumdd, g3, bb3, a4, wb4);
    b4_kernel<<<128, 256, 0, stream>>>(a4, wb4, sumd, sumdd, g4, bb4, (float*)d_out);
  }
}

// Round 4
// 269.771 us; speedup vs baseline: 2.2304x; 2.2304x over previous
//
#include <hip/hip_runtime.h>
#include <stdint.h>

// Binarized 5-layer MLP, B=32768, dims 784->256->256->256->256->10.
// Round 14: persistent REGULAR-launch fused kernel + zero-cache-op barrier.
// Evidence r12/r13: barrier mechanism swap (cg.sync -> naive atomic barrier)
// changed nothing (424 vs 431us) => cost is the shared primitives: agent
// release fence (L2 writeback scan x512), 512 same-line RMWs, acquire-load
// polling on the same line. Also bench-total minus kernel-time ~= 155us in
// both rounds => hipLaunchCooperativeKernel dispatch tax.
// Design: ALL cross-block data is read-only (x, packed weights via kernel
// boundary) or device-scope atomics (stats, executed at MALL). So the grid
// barrier needs NO cache maintenance:
//   - __syncthreads drains each wave's vmcnt (atomics acked at MALL)
//   - hierarchical relaxed arrivals: 32 groups x16 -> root x32, lines 256B apart
//   - relaxed polling on 16 replicated generation lines (s_sleep backoff)
//   - stats READS are relaxed agent-scope atomic loads (MALL-fresh, no inv)
// Regular launch (no coop tax). Co-residency by construction: 512 blocks,
// capacity 3/CU = 768 (launch_bounds(256,3), 68 VGPR, 12.8KB LDS).
// Math (verified r12/r13, absmax 0.00195): d = popcount(a XOR w);
// binarize(BN(h)) == (A*d + C >= 0), A = -2*g*s, C = 2*g*s*mean_d + b,
// s = rsqrt(4*(E[d^2]-E[d]^2)+eps). Stats = exact integer sums in 16
// replicated atomic slots; consumers reduce replicas.

typedef unsigned long long u64;

#define NREP 16
#define GRID_BLOCKS 512
#define NGROUPS 32      // arrival tree: 32 groups of 16 blocks
#define GROUP_SZ 16

// ---- workspace layout (bytes) ----
#define OFF_WB0   0u          // u64 [16][256] = 32768 (words 0..12 used)
#define OFF_WB1   32768u      // u64 [4][256] = 8192
#define OFF_WB2   40960u
#define OFF_WB3   49152u
#define OFF_WB4   57344u      // u64 [4][16] = 512 (10 cols used)
#define OFF_SUMD  57856u      // int32 [16][5][256] = 81920
#define OFF_SUMDD 139776u     // u64   [16][5][256] = 163840
#define OFF_BAR   303616u     // 49 lines x 256B: 32 group cnts, 1 root, 16 gen
#define ZERO_INT4 16144       // (81920+163840+12544)/16, zeroed from OFF_SUMD

// 784-elem row -> 13 packed u64 words (consistent permuted bit order).
__device__ __forceinline__ u64 pack784_sel(const float* __restrict__ src,
                                           float thr, int lane) {
  u64 w[13];
  const float4* s4 = (const float4*)src;
#pragma unroll
  for (int j = 0; j < 3; ++j) {
    float4 v = s4[j * 64 + lane];
    w[4*j+0] = __ballot(v.x >= thr);
    w[4*j+1] = __ballot(v.y >= thr);
    w[4*j+2] = __ballot(v.z >= thr);
    w[4*j+3] = __ballot(v.w >= thr);
  }
  float4 v = make_float4(-1.f, -1.f, -1.f, -1.f);
  if (lane < 4) v = s4[192 + lane];
  u64 m0 = __ballot(v.x >= thr) & 0xFull;
  u64 m1 = __ballot(v.y >= thr) & 0xFull;
  u64 m2 = __ballot(v.z >= thr) & 0xFull;
  u64 m3 = __ballot(v.w >= thr) & 0xFull;
  w[12] = m0 | (m1 << 4) | (m2 << 8) | (m3 << 12);
  u64 sel = 0;
#pragma unroll
  for (int i = 0; i < 13; ++i) sel = (lane == i) ? w[i] : sel;
  return sel;
}

// 256-elem row -> 4 packed u64 words; bit l of word j <-> element 64*j+l.
__device__ __forceinline__ u64 pack256_sel(const float* __restrict__ src, int lane) {
  u64 w[4];
#pragma unroll
  for (int j = 0; j < 4; ++j) w[j] = __ballot(src[j * 64 + lane] >= 0.0f);
  u64 sel = 0;
#pragma unroll
  for (int i = 0; i < 4; ++i) sel = (lane == i) ? w[i] : sel;
  return sel;
}

// Reduce the 16 stats replicas for (layer, col) via MALL-fresh atomic loads.
__device__ __forceinline__ void bn_gs_md(const int* __restrict__ sumd_rep,
                                         const u64* __restrict__ sumdd_rep,
                                         int layer, int col,
                                         const float* __restrict__ g,
                                         float& gs, float& md_out) {
  long long sd = 0; u64 sdd = 0;
#pragma unroll
  for (int r = 0; r < NREP; ++r) {
    sd  += __hip_atomic_load(&sumd_rep [(r * 5 + layer) * 256 + col],
                             __ATOMIC_RELAXED, __HIP_MEMORY_SCOPE_AGENT);
    sdd += __hip_atomic_load(&sumdd_rep[(r * 5 + layer) * 256 + col],
                             __ATOMIC_RELAXED, __HIP_MEMORY_SCOPE_AGENT);
  }
  double md  = (double)sd  * (1.0 / 32768.0);
  double mdd = (double)sdd * (1.0 / 32768.0);
  float var = (float)(4.0 * (mdd - md * md));
  float s   = rsqrtf(var + 1e-5f);
  gs = g[col] * s;
  md_out = (float)md;
}

#define DPK_SET(r, d) do { if ((r) & 1) dpk[(r) >> 1] |= ((unsigned)(d)) << 16; \
                           else dpk[(r) >> 1] = (unsigned)(d); } while (0)
#define DPK_GET(r) ((int)((dpk[(r) >> 1] >> (((r) & 1) * 16)) & 0xFFFFu))

// Stats add: force the RETURNING atomic form so vmcnt-retire == completed at
// the MALL (hard guarantee for the barrier's publication ordering).
__device__ __forceinline__ void stats_add(int* pd, u64* pdd, int sd, u64 sdd) {
  int o1 = atomicAdd(pd, sd);
  u64 o2 = atomicAdd(pdd, sdd);
  asm volatile("" :: "v"(o1), "v"(o2));
}

// ---- zero-cache-op hierarchical grid barrier ----
// Monotonic counters (no reset races); phase = 1..5. Lines are 256B apart:
//   bar[g*64]        g<32  : group arrival counters
//   bar[32*64]             : root counter
//   bar[(33+r)*64]   r<16  : generation replicas
// __syncthreads() drains each wave's vmcnt (compiler emits waitcnt before
// s_barrier), so all this block's stats atomics are MALL-complete before
// tid0 publishes arrival. Polling is RELAXED on a replica line (no inv, no
// contention with arrival RMWs). No fences: consumers re-read stats straight
// from the MALL via atomic loads.
__device__ __forceinline__ void grid_barrier(unsigned* bar, unsigned phase, int b) {
  __syncthreads();
  if (threadIdx.x == 0) {
    asm volatile("s_waitcnt vmcnt(0)" ::: "memory");
    const unsigned g = (unsigned)b >> 4;           // b / GROUP_SZ
    unsigned a = __hip_atomic_fetch_add(&bar[g * 64], 1u, __ATOMIC_RELAXED,
                                        __HIP_MEMORY_SCOPE_AGENT) + 1u;
    bool released = false;
    if (a == phase * GROUP_SZ) {                   // last of my group, this phase
      unsigned r = __hip_atomic_fetch_add(&bar[32 * 64], 1u, __ATOMIC_RELAXED,
                                          __HIP_MEMORY_SCOPE_AGENT) + 1u;
      if (r == phase * NGROUPS) {                  // last overall: release
#pragma unroll
        for (int i = 0; i < 16; ++i)
          __hip_atomic_store(&bar[(33 + i) * 64], phase, __ATOMIC_RELAXED,
                             __HIP_MEMORY_SCOPE_AGENT);
        released = true;
      }
    }
    if (!released) {
      const unsigned* genp = &bar[(33 + (b & 15)) * 64];
      while (__hip_atomic_load(genp, __ATOMIC_RELAXED,
                               __HIP_MEMORY_SCOPE_AGENT) < phase)
        __builtin_amdgcn_s_sleep(8);
    }
  }
  __syncthreads();
}

// ================= prep: pack weights + zero stats & barrier =================
__global__ __launch_bounds__(256) void pack_weights(
    const float* __restrict__ W0, const float* __restrict__ W1,
    const float* __restrict__ W2, const float* __restrict__ W3,
    const float* __restrict__ W4,
    u64* __restrict__ wb0, u64* __restrict__ wb1, u64* __restrict__ wb2,
    u64* __restrict__ wb3, u64* __restrict__ wb4, int4* __restrict__ zeroRgn) {
  const int b = blockIdx.x, tid = threadIdx.x;
  const int lane = tid & 63, wave = tid >> 6;
  int gid = b * 256 + tid;
  if (gid < ZERO_INT4) zeroRgn[gid] = make_int4(0, 0, 0, 0);
  if (b < 64) {
    int row = b * 4 + wave;
    u64 sel = pack784_sel(W0 + (size_t)row * 784, 0.0f, lane);
    if (lane < 13) wb0[lane * 256 + row] = sel;
  } else if (b < 128) {
    int row = (b - 64) * 4 + wave;
    u64 sel = pack256_sel(W1 + (size_t)row * 256, lane);
    if (lane < 4) wb1[lane * 256 + row] = sel;
  } else if (b < 192) {
    int row = (b - 128) * 4 + wave;
    u64 sel = pack256_sel(W2 + (size_t)row * 256, lane);
    if (lane < 4) wb2[lane * 256 + row] = sel;
  } else if (b < 256) {
    int row = (b - 192) * 4 + wave;
    u64 sel = pack256_sel(W3 + (size_t)row * 256, lane);
    if (lane < 4) wb3[lane * 256 + row] = sel;
  } else {
    for (int row = wave; row < 10; row += 4) {
      u64 sel = pack256_sel(W4 + (size_t)row * 256, lane);
      if (lane < 4) wb4[lane * 16 + row] = sel;
    }
  }
}

// ================= fused persistent kernel (regular launch) =================
__global__ __launch_bounds__(256, 3) void fused_bnn(
    const float* __restrict__ x,
    const float* __restrict__ g0, const float* __restrict__ g1,
    const float* __restrict__ g2, const float* __restrict__ g3,
    const float* __restrict__ g4,
    const float* __restrict__ bb0, const float* __restrict__ bb1,
    const float* __restrict__ bb2, const float* __restrict__ bb3,
    const float* __restrict__ bb4,
    float* __restrict__ out, char* __restrict__ ws) {
  u64* wb0 = (u64*)(ws + OFF_WB0);
  u64* wb1 = (u64*)(ws + OFF_WB1);
  u64* wb2 = (u64*)(ws + OFF_WB2);
  u64* wb3 = (u64*)(ws + OFF_WB3);
  u64* wb4 = (u64*)(ws + OFF_WB4);
  int* sumd  = (int*)(ws + OFF_SUMD);
  u64* sumdd = (u64*)(ws + OFF_SUMDD);
  unsigned* bar = (unsigned*)(ws + OFF_BAR);

  const int b = blockIdx.x, tid = threadIdx.x;
  const int lane = tid & 63, wave = tid >> 6;
  const int row0 = b * 64;            // this block owns rows row0..row0+63
  const int rep = b & (NREP - 1);

  __shared__ u64 aw[64 * 16];         // 8 KB: layer-0 packed rows (13/16 words)
  __shared__ u64 bits[64 * 4];        // 2 KB: current activation bits
  __shared__ float sY[640];           // 2.5 KB: layer-4 pre-softmax

  unsigned dpk[32];                   // 64 d-values, 2x16b packed, registers

  // ---- P1: layer 0 — pack 64 x-rows into LDS, d0 -> dpk, stats0
  {
    u64 w0  = wb0[ 0 * 256 + tid], w1  = wb0[ 1 * 256 + tid];
    u64 w2  = wb0[ 2 * 256 + tid], w3  = wb0[ 3 * 256 + tid];
    u64 w4  = wb0[ 4 * 256 + tid], w5  = wb0[ 5 * 256 + tid];
    u64 w6  = wb0[ 6 * 256 + tid], w7  = wb0[ 7 * 256 + tid];
    u64 w8  = wb0[ 8 * 256 + tid], w9  = wb0[ 9 * 256 + tid];
    u64 w10 = wb0[10 * 256 + tid], w11 = wb0[11 * 256 + tid];
    u64 w12 = wb0[12 * 256 + tid];
    const float* base = x + (size_t)(row0 + wave * 16) * 784;  // 16 rows/wave
#pragma unroll 2
    for (int it = 0; it < 16; ++it) {
      u64 sel = pack784_sel(base + (size_t)it * 784, 0.5f, lane);
      if (lane < 13) aw[(wave * 16 + it) * 16 + lane] = sel;   // words 13..15 never read
    }
    __syncthreads();
    int sd = 0; unsigned sdd = 0;   // 64*784^2 = 39.3M fits u32
#pragma unroll
    for (int r = 0; r < 64; ++r) {
      const u64* ap = &aw[r * 16];
      int d = __popcll(ap[0] ^ w0)   + __popcll(ap[1] ^ w1)
            + __popcll(ap[2] ^ w2)   + __popcll(ap[3] ^ w3)
            + __popcll(ap[4] ^ w4)   + __popcll(ap[5] ^ w5)
            + __popcll(ap[6] ^ w6)   + __popcll(ap[7] ^ w7)
            + __popcll(ap[8] ^ w8)   + __popcll(ap[9] ^ w9)
            + __popcll(ap[10] ^ w10) + __popcll(ap[11] ^ w11)
            + __popcll(ap[12] ^ w12);
      DPK_SET(r, d);
      sd += d; sdd += (unsigned)(d * d);
    }
    stats_add(&sumd[(rep * 5 + 0) * 256 + tid],
              &sumdd[(rep * 5 + 0) * 256 + tid], sd, (u64)sdd);
  }
  grid_barrier(bar, 1, b);

  // ---- P2..P4: layers 1..3 — binarize dpk -> bits -> new dpk + next stats
#pragma unroll
  for (int k = 0; k < 3; ++k) {
    const float* gk  = (k == 0) ? g0  : (k == 1) ? g1  : g2;
    const float* bk  = (k == 0) ? bb0 : (k == 1) ? bb1 : bb2;
    const u64*   wbN = (k == 0) ? wb1 : (k == 1) ? wb2 : wb3;
    float gs, md;
    bn_gs_md(sumd, sumdd, k, tid, gk, gs, md);
    const float A = -2.0f * gs;
    const float C = fmaf(gs, 2.0f * md, bk[tid]);
#pragma unroll
    for (int r = 0; r < 64; ++r) {
      bool bit = fmaf(A, (float)DPK_GET(r), C) >= 0.0f;
      u64 m = __ballot(bit);
      if (lane == 0) bits[r * 4 + wave] = m;
    }
    __syncthreads();
    u64 wn0 = wbN[0 * 256 + tid], wn1 = wbN[1 * 256 + tid];
    u64 wn2 = wbN[2 * 256 + tid], wn3 = wbN[3 * 256 + tid];
    int sd = 0; unsigned sdd = 0;   // 64 * 256^2 = 4.2M fits u32
#pragma unroll
    for (int r = 0; r < 64; ++r) {
      int d = __popcll(bits[r*4+0] ^ wn0) + __popcll(bits[r*4+1] ^ wn1)
            + __popcll(bits[r*4+2] ^ wn2) + __popcll(bits[r*4+3] ^ wn3);
      DPK_SET(r, d);
      sd += d; sdd += (unsigned)(d * d);
    }
    stats_add(&sumd[(rep * 5 + k + 1) * 256 + tid],
              &sumdd[(rep * 5 + k + 1) * 256 + tid], sd, (u64)sdd);
    grid_barrier(bar, 2 + k, b);
  }

  // ---- P5: layer 4 — binarize d3 -> bits -> d4 (10 cols, in dpk of tid<10)
  {
    float gs, md;
    bn_gs_md(sumd, sumdd, 3, tid, g3, gs, md);
    const float A = -2.0f * gs;
    const float C = fmaf(gs, 2.0f * md, bb3[tid]);
#pragma unroll
    for (int r = 0; r < 64; ++r) {
      bool bit = fmaf(A, (float)DPK_GET(r), C) >= 0.0f;
      u64 m = __ballot(bit);
      if (lane == 0) bits[r * 4 + wave] = m;
    }
    __syncthreads();
    if (tid < 10) {
      u64 wn0 = wb4[0 * 16 + tid], wn1 = wb4[1 * 16 + tid];
      u64 wn2 = wb4[2 * 16 + tid], wn3 = wb4[3 * 16 + tid];
      int sd = 0; unsigned sdd = 0;
#pragma unroll
      for (int r = 0; r < 64; ++r) {
        int d = __popcll(bits[r*4+0] ^ wn0) + __popcll(bits[r*4+1] ^ wn1)
              + __popcll(bits[r*4+2] ^ wn2) + __popcll(bits[r*4+3] ^ wn3);
        DPK_SET(r, d);
        sd += d; sdd += (unsigned)(d * d);
      }
      stats_add(&sumd[(rep * 5 + 4) * 256 + tid],
                &sumdd[(rep * 5 + 4) * 256 + tid], sd, (u64)sdd);
    }
  }
  grid_barrier(bar, 5, b);

  // ---- P6: BN4 + softmax + store
  {
    if (tid < 10) {
      float gs, md;
      bn_gs_md(sumd, sumdd, 4, tid, g4, gs, md);
      const float A = -2.0f * gs;
      const float C = fmaf(gs, 2.0f * md, bb4[tid]);
#pragma unroll
      for (int r = 0; r < 64; ++r)
        sY[r * 10 + tid] = fmaf(A, (float)DPK_GET(r), C);
    }
    __syncthreads();
    if (tid < 64) {
      float y[10]; float mx = -1e30f;
#pragma unroll
      for (int c = 0; c < 10; ++c) { y[c] = sY[tid * 10 + c]; mx = fmaxf(mx, y[c]); }
      float sum = 0.0f;
#pragma unroll
      for (int c = 0; c < 10; ++c) { y[c] = __expf(y[c] - mx); sum += y[c]; }
      float inv = 1.0f / sum;
      float* op = out + (size_t)(row0 + tid) * 10;
#pragma unroll
      for (int c = 0; c < 10; ++c) op[c] = y[c] * inv;
    }
  }
}

// ---------------- host ----------------
extern "C" void kernel_launch(void* const* d_in, const int* in_sizes, int n_in,
                              void* d_out, int out_size, void* d_ws, size_t ws_size,
                              hipStream_t stream) {
  (void)in_sizes; (void)n_in; (void)out_size; (void)ws_size;
  const float* x   = (const float*)d_in[0];
  const float* W0  = (const float*)d_in[1];
  const float* g0  = (const float*)d_in[2];
  const float* bb0 = (const float*)d_in[3];
  const float* W1  = (const float*)d_in[4];
  const float* g1  = (const float*)d_in[5];
  const float* bb1 = (const float*)d_in[6];
  const float* W2  = (const float*)d_in[7];
  const float* g2  = (const float*)d_in[8];
  const float* bb2 = (const float*)d_in[9];
  const float* W3  = (const float*)d_in[10];
  const float* g3  = (const float*)d_in[11];
  const float* bb3 = (const float*)d_in[12];
  const float* W4  = (const float*)d_in[13];
  const float* g4  = (const float*)d_in[14];
  const float* bb4 = (const float*)d_in[15];
  char* ws = (char*)d_ws;

  u64* wb0 = (u64*)(ws + OFF_WB0);
  u64* wb1 = (u64*)(ws + OFF_WB1);
  u64* wb2 = (u64*)(ws + OFF_WB2);
  u64* wb3 = (u64*)(ws + OFF_WB3);
  u64* wb4 = (u64*)(ws + OFF_WB4);

  pack_weights<<<257, 256, 0, stream>>>(W0, W1, W2, W3, W4,
                                        wb0, wb1, wb2, wb3, wb4,
                                        (int4*)(ws + OFF_SUMD));
  fused_bnn<<<GRID_BLOCKS, 256, 0, stream>>>(
      x, g0, g1, g2, g3, g4, bb0, bb1, bb2, bb3, bb4,
      (float*)d_out, ws);
}

// Round 6
// 268.344 us; speedup vs baseline: 2.2423x; 1.0053x over previous
//
#include <hip/hip_runtime.h>
#include <stdint.h>

// Binarized 5-layer MLP, B=32768, dims 784->256->256->256->256->10.
// Round 16: deadlock-proof occupancy experiment.
// r15 (1024 blocks, launch_bounds(256,4)) -> "container failed twice" = likely
// spin-barrier deadlock: (256,4) allows 128 VGPR -> capacity could be EXACTLY
// 4 blocks/CU = 1024 = zero margin. Lesson: never launch a spin-barrier kernel
// without VERIFIED occupancy margin.
// This round: two instantiations of the same templated kernel:
//   fused_bnn<1024,32> (occupancy experiment, launch_bounds(256,4))
//   fused_bnn<512,64>  (byte-identical to r14's proven 131us kernel, (256,3))
// Host queries hipOccupancyMaxActiveBlocksPerMultiprocessor (host-only, graph-
// capture-safe) once; launches the 1024 variant only if capacity >= 5/CU
// (>=1280 slots for 1024 blocks). Either path is co-residency-guaranteed.
// Barrier design unchanged (r14-verified, 433us->131us): all cross-block data
// is read-only (x, packed weights via kernel boundary) or device-scope atomics
// at MALL; barrier = hierarchical relaxed arrivals (NBLK/16 groups x16 -> root,
// lines 256B apart) + relaxed poll on 16 replicated gen lines; no cache ops.
// Math (verified r12-r14, absmax 0.00195): d = popcount(a XOR w);
// binarize(BN(h)) == (A*d + C >= 0), A = -2*g*s, C = 2*g*s*mean_d + b,
// s = rsqrt(4*(E[d^2]-E[d]^2)+eps). Stats = exact integer sums in 16
// replicated atomic slots; consumers reduce replicas.

typedef unsigned long long u64;

#define NREP 16

// ---- workspace layout (bytes) ----
#define OFF_WB0   0u          // u64 [16][256] = 32768 (words 0..12 used)
#define OFF_WB1   32768u      // u64 [4][256] = 8192
#define OFF_WB2   40960u
#define OFF_WB3   49152u
#define OFF_WB4   57344u      // u64 [4][16] = 512 (10 cols used)
#define OFF_SUMD  57856u      // int32 [16][5][256] = 81920
#define OFF_SUMDD 139776u     // u64   [16][5][256] = 163840
#define OFF_BAR   303616u     // 81 lines x 256B: <=64 group cnts, 1 root, 16 gen
#define ZERO_INT4 16656       // (81920+163840+81*256)/16, zeroed from OFF_SUMD

// 784-elem row -> 13 packed u64 words (consistent permuted bit order).
__device__ __forceinline__ u64 pack784_sel(const float* __restrict__ src,
                                           float thr, int lane) {
  u64 w[13];
  const float4* s4 = (const float4*)src;
#pragma unroll
  for (int j = 0; j < 3; ++j) {
    float4 v = s4[j * 64 + lane];
    w[4*j+0] = __ballot(v.x >= thr);
    w[4*j+1] = __ballot(v.y >= thr);
    w[4*j+2] = __ballot(v.z >= thr);
    w[4*j+3] = __ballot(v.w >= thr);
  }
  float4 v = make_float4(-1.f, -1.f, -1.f, -1.f);
  if (lane < 4) v = s4[192 + lane];
  u64 m0 = __ballot(v.x >= thr) & 0xFull;
  u64 m1 = __ballot(v.y >= thr) & 0xFull;
  u64 m2 = __ballot(v.z >= thr) & 0xFull;
  u64 m3 = __ballot(v.w >= thr) & 0xFull;
  w[12] = m0 | (m1 << 4) | (m2 << 8) | (m3 << 12);
  u64 sel = 0;
#pragma unroll
  for (int i = 0; i < 13; ++i) sel = (lane == i) ? w[i] : sel;
  return sel;
}

// 256-elem row -> 4 packed u64 words; bit l of word j <-> element 64*j+l.
__device__ __forceinline__ u64 pack256_sel(const float* __restrict__ src, int lane) {
  u64 w[4];
#pragma unroll
  for (int j = 0; j < 4; ++j) w[j] = __ballot(src[j * 64 + lane] >= 0.0f);
  u64 sel = 0;
#pragma unroll
  for (int i = 0; i < 4; ++i) sel = (lane == i) ? w[i] : sel;
  return sel;
}

// Reduce the 16 stats replicas for (layer, col) via MALL-fresh atomic loads.
__device__ __forceinline__ void bn_gs_md(const int* __restrict__ sumd_rep,
                                         const u64* __restrict__ sumdd_rep,
                                         int layer, int col,
                                         const float* __restrict__ g,
                                         float& gs, float& md_out) {
  long long sd = 0; u64 sdd = 0;
#pragma unroll
  for (int r = 0; r < NREP; ++r) {
    sd  += __hip_atomic_load(&sumd_rep [(r * 5 + layer) * 256 + col],
                             __ATOMIC_RELAXED, __HIP_MEMORY_SCOPE_AGENT);
    sdd += __hip_atomic_load(&sumdd_rep[(r * 5 + layer) * 256 + col],
                             __ATOMIC_RELAXED, __HIP_MEMORY_SCOPE_AGENT);
  }
  double md  = (double)sd  * (1.0 / 32768.0);
  double mdd = (double)sdd * (1.0 / 32768.0);
  float var = (float)(4.0 * (mdd - md * md));
  float s   = rsqrtf(var + 1e-5f);
  gs = g[col] * s;
  md_out = (float)md;
}

#define DPK_SET(r, d) do { if ((r) & 1) dpk[(r) >> 1] |= ((unsigned)(d)) << 16; \
                           else dpk[(r) >> 1] = (unsigned)(d); } while (0)
#define DPK_GET(r) ((int)((dpk[(r) >> 1] >> (((r) & 1) * 16)) & 0xFFFFu))

// Stats add: returning atomic form so vmcnt-retire == completed at the MALL.
__device__ __forceinline__ void stats_add(int* pd, u64* pdd, int sd, u64 sdd) {
  int o1 = atomicAdd(pd, sd);
  u64 o2 = atomicAdd(pdd, sdd);
  asm volatile("" :: "v"(o1), "v"(o2));
}

// ---- zero-cache-op hierarchical grid barrier ----
// Monotonic counters; phase = 1..5. Lines 256B apart:
//   bar[g*64]            g<NGRP : group arrival counters
//   bar[NGRP*64]                : root counter
//   bar[(NGRP+1+r)*64]   r<16   : generation replicas
// __syncthreads() drains each wave's vmcnt before tid0 publishes arrival;
// polling is RELAXED on a replica line; consumers re-read stats at the MALL.
template<int NBLK>
__device__ __forceinline__ void grid_barrier(unsigned* bar, unsigned phase, int b) {
  constexpr unsigned NGRP = NBLK / 16;
  __syncthreads();
  if (threadIdx.x == 0) {
    asm volatile("s_waitcnt vmcnt(0)" ::: "memory");
    const unsigned g = (unsigned)b >> 4;           // b / 16
    unsigned a = __hip_atomic_fetch_add(&bar[g * 64], 1u, __ATOMIC_RELAXED,
                                        __HIP_MEMORY_SCOPE_AGENT) + 1u;
    bool released = false;
    if (a == phase * 16u) {                        // last of my group, this phase
      unsigned r = __hip_atomic_fetch_add(&bar[NGRP * 64], 1u, __ATOMIC_RELAXED,
                                          __HIP_MEMORY_SCOPE_AGENT) + 1u;
      if (r == phase * NGRP) {                     // last overall: release
#pragma unroll
        for (int i = 0; i < 16; ++i)
          __hip_atomic_store(&bar[(NGRP + 1 + i) * 64], phase, __ATOMIC_RELAXED,
                             __HIP_MEMORY_SCOPE_AGENT);
        released = true;
      }
    }
    if (!released) {
      const unsigned* genp = &bar[(NGRP + 1 + (b & 15)) * 64];
      while (__hip_atomic_load(genp, __ATOMIC_RELAXED,
                               __HIP_MEMORY_SCOPE_AGENT) < phase)
        __builtin_amdgcn_s_sleep(8);
    }
  }
  __syncthreads();
}

// ================= prep: pack weights + zero stats & barrier =================
__global__ __launch_bounds__(256) void pack_weights(
    const float* __restrict__ W0, const float* __restrict__ W1,
    const float* __restrict__ W2, const float* __restrict__ W3,
    const float* __restrict__ W4,
    u64* __restrict__ wb0, u64* __restrict__ wb1, u64* __restrict__ wb2,
    u64* __restrict__ wb3, u64* __restrict__ wb4, int4* __restrict__ zeroRgn) {
  const int b = blockIdx.x, tid = threadIdx.x;
  const int lane = tid & 63, wave = tid >> 6;
  int gid = b * 256 + tid;
  if (gid < ZERO_INT4) zeroRgn[gid] = make_int4(0, 0, 0, 0);
  if (b < 64) {
    int row = b * 4 + wave;
    u64 sel = pack784_sel(W0 + (size_t)row * 784, 0.0f, lane);
    if (lane < 13) wb0[lane * 256 + row] = sel;
  } else if (b < 128) {
    int row = (b - 64) * 4 + wave;
    u64 sel = pack256_sel(W1 + (size_t)row * 256, lane);
    if (lane < 4) wb1[lane * 256 + row] = sel;
  } else if (b < 192) {
    int row = (b - 128) * 4 + wave;
    u64 sel = pack256_sel(W2 + (size_t)row * 256, lane);
    if (lane < 4) wb2[lane * 256 + row] = sel;
  } else if (b < 256) {
    int row = (b - 192) * 4 + wave;
    u64 sel = pack256_sel(W3 + (size_t)row * 256, lane);
    if (lane < 4) wb3[lane * 256 + row] = sel;
  } else {
    for (int row = wave; row < 10; row += 4) {
      u64 sel = pack256_sel(W4 + (size_t)row * 256, lane);
      if (lane < 4) wb4[lane * 16 + row] = sel;
    }
  }
}

// ================= fused persistent kernel (regular launch) =================
// NBLK x RWS rows; NBLK*RWS == 32768. launch_bounds: 4 waves/EU floor for the
// 1024-block variant (needs 4 blocks/CU), 3 for the 512-block one (needs 2).
template<int NBLK, int RWS>
__global__ __launch_bounds__(256, (NBLK >= 1024) ? 4 : 3) void fused_bnn(
    const float* __restrict__ x,
    const float* __restrict__ g0, const float* __restrict__ g1,
    const float* __restrict__ g2, const float* __restrict__ g3,
    const float* __restrict__ g4,
    const float* __restrict__ bb0, const float* __restrict__ bb1,
    const float* __restrict__ bb2, const float* __restrict__ bb3,
    const float* __restrict__ bb4,
    float* __restrict__ out, char* __restrict__ ws) {
  u64* wb0 = (u64*)(ws + OFF_WB0);
  u64* wb1 = (u64*)(ws + OFF_WB1);
  u64* wb2 = (u64*)(ws + OFF_WB2);
  u64* wb3 = (u64*)(ws + OFF_WB3);
  u64* wb4 = (u64*)(ws + OFF_WB4);
  int* sumd  = (int*)(ws + OFF_SUMD);
  u64* sumdd = (u64*)(ws + OFF_SUMDD);
  unsigned* bar = (unsigned*)(ws + OFF_BAR);

  const int b = blockIdx.x, tid = threadIdx.x;
  const int lane = tid & 63, wave = tid >> 6;
  const int row0 = b * RWS;           // this block owns rows row0..row0+RWS-1
  const int rep = b & (NREP - 1);
  constexpr int RPW = RWS / 4;        // rows packed per wave in P1

  __shared__ u64 aw[RWS * 16];        // layer-0 packed rows (13/16 words used)
  __shared__ u64 bits[RWS * 4];       // current activation bits
  __shared__ float sY[RWS * 10];      // layer-4 pre-softmax

  unsigned dpk[RWS / 2];              // RWS d-values, 2x16b packed, registers

  // ---- P1: layer 0 — pack RWS x-rows into LDS, d0 -> dpk, stats0
  {
    u64 w0  = wb0[ 0 * 256 + tid], w1  = wb0[ 1 * 256 + tid];
    u64 w2  = wb0[ 2 * 256 + tid], w3  = wb0[ 3 * 256 + tid];
    u64 w4  = wb0[ 4 * 256 + tid], w5  = wb0[ 5 * 256 + tid];
    u64 w6  = wb0[ 6 * 256 + tid], w7  = wb0[ 7 * 256 + tid];
    u64 w8  = wb0[ 8 * 256 + tid], w9  = wb0[ 9 * 256 + tid];
    u64 w10 = wb0[10 * 256 + tid], w11 = wb0[11 * 256 + tid];
    u64 w12 = wb0[12 * 256 + tid];
    const float* base = x + (size_t)(row0 + wave * RPW) * 784;
#pragma unroll 2
    for (int it = 0; it < RPW; ++it) {
      u64 sel = pack784_sel(base + (size_t)it * 784, 0.5f, lane);
      if (lane < 13) aw[(wave * RPW + it) * 16 + lane] = sel;  // words 13..15 never read
    }
    __syncthreads();
    int sd = 0; unsigned sdd = 0;   // RWS*784^2 <= 39.3M fits u32
#pragma unroll
    for (int r = 0; r < RWS; ++r) {
      const u64* ap = &aw[r * 16];
      int d = __popcll(ap[0] ^ w0)   + __popcll(ap[1] ^ w1)
            + __popcll(ap[2] ^ w2)   + __popcll(ap[3] ^ w3)
            + __popcll(ap[4] ^ w4)   + __popcll(ap[5] ^ w5)
            + __popcll(ap[6] ^ w6)   + __popcll(ap[7] ^ w7)
            + __popcll(ap[8] ^ w8)   + __popcll(ap[9] ^ w9)
            + __popcll(ap[10] ^ w10) + __popcll(ap[11] ^ w11)
            + __popcll(ap[12] ^ w12);
      DPK_SET(r, d);
      sd += d; sdd += (unsigned)(d * d);
    }
    stats_add(&sumd[(rep * 5 + 0) * 256 + tid],
              &sumdd[(rep * 5 + 0) * 256 + tid], sd, (u64)sdd);
  }
  grid_barrier<NBLK>(bar, 1, b);

  // ---- P2..P4: layers 1..3 — binarize dpk -> bits -> new dpk + next stats
#pragma unroll
  for (int k = 0; k < 3; ++k) {
    const float* gk  = (k == 0) ? g0  : (k == 1) ? g1  : g2;
    const float* bk  = (k == 0) ? bb0 : (k == 1) ? bb1 : bb2;
    const u64*   wbN = (k == 0) ? wb1 : (k == 1) ? wb2 : wb3;
    float gs, md;
    bn_gs_md(sumd, sumdd, k, tid, gk, gs, md);
    const float A = -2.0f * gs;
    const float C = fmaf(gs, 2.0f * md, bk[tid]);
#pragma unroll
    for (int r = 0; r < RWS; ++r) {
      bool bit = fmaf(A, (float)DPK_GET(r), C) >= 0.0f;
      u64 m = __ballot(bit);
      if (lane == 0) bits[r * 4 + wave] = m;
    }
    __syncthreads();
    u64 wn0 = wbN[0 * 256 + tid], wn1 = wbN[1 * 256 + tid];
    u64 wn2 = wbN[2 * 256 + tid], wn3 = wbN[3 * 256 + tid];
    int sd = 0; unsigned sdd = 0;   // RWS * 256^2 <= 4.2M fits u32
#pragma unroll
    for (int r = 0; r < RWS; ++r) {
      int d = __popcll(bits[r*4+0] ^ wn0) + __popcll(bits[r*4+1] ^ wn1)
            + __popcll(bits[r*4+2] ^ wn2) + __popcll(bits[r*4+3] ^ wn3);
      DPK_SET(r, d);
      sd += d; sdd += (unsigned)(d * d);
    }
    stats_add(&sumd[(rep * 5 + k + 1) * 256 + tid],
              &sumdd[(rep * 5 + k + 1) * 256 + tid], sd, (u64)sdd);
    grid_barrier<NBLK>(bar, 2 + k, b);
  }

  // ---- P5: layer 4 — binarize d3 -> bits -> d4 (10 cols, in dpk of tid<10)
  {
    float gs, md;
    bn_gs_md(sumd, sumdd, 3, tid, g3, gs, md);
    const float A = -2.0f * gs;
    const float C = fmaf(gs, 2.0f * md, bb3[tid]);
#pragma unroll
    for (int r = 0; r < RWS; ++r) {
      bool bit = fmaf(A, (float)DPK_GET(r), C) >= 0.0f;
      u64 m = __ballot(bit);
      if (lane == 0) bits[r * 4 + wave] = m;
    }
    __syncthreads();
    if (tid < 10) {
      u64 wn0 = wb4[0 * 16 + tid], wn1 = wb4[1 * 16 + tid];
      u64 wn2 = wb4[2 * 16 + tid], wn3 = wb4[3 * 16 + tid];
      int sd = 0; unsigned sdd = 0;
#pragma unroll
      for (int r = 0; r < RWS; ++r) {
        int d = __popcll(bits[r*4+0] ^ wn0) + __popcll(bits[r*4+1] ^ wn1)
              + __popcll(bits[r*4+2] ^ wn2) + __popcll(bits[r*4+3] ^ wn3);
        DPK_SET(r, d);
        sd += d; sdd += (unsigned)(d * d);
      }
      stats_add(&sumd[(rep * 5 + 4) * 256 + tid],
                &sumdd[(rep * 5 + 4) * 256 + tid], sd, (u64)sdd);
    }
  }
  grid_barrier<NBLK>(bar, 5, b);

  // ---- P6: BN4 + softmax + store
  {
    if (tid < 10) {
      float gs, md;
      bn_gs_md(sumd, sumdd, 4, tid, g4, gs, md);
      const float A = -2.0f * gs;
      const float C = fmaf(gs, 2.0f * md, bb4[tid]);
#pragma unroll
      for (int r = 0; r < RWS; ++r)
        sY[r * 10 + tid] = fmaf(A, (float)DPK_GET(r), C);
    }
    __syncthreads();
    if (tid < RWS) {
      float y[10]; float mx = -1e30f;
#pragma unroll
      for (int c = 0; c < 10; ++c) { y[c] = sY[tid * 10 + c]; mx = fmaxf(mx, y[c]); }
      float sum = 0.0f;
#pragma unroll
      for (int c = 0; c < 10; ++c) { y[c] = __expf(y[c] - mx); sum += y[c]; }
      float inv = 1.0f / sum;
      float* op = out + (size_t)(row0 + tid) * 10;
#pragma unroll
      for (int c = 0; c < 10; ++c) op[c] = y[c] * inv;
    }
  }
}

// ---------------- host ----------------
extern "C" void kernel_launch(void* const* d_in, const int* in_sizes, int n_in,
                              void* d_out, int out_size, void* d_ws, size_t ws_size,
                              hipStream_t stream) {
  (void)in_sizes; (void)n_in; (void)out_size; (void)ws_size;
  const float* x   = (const float*)d_in[0];
  const float* W0  = (const float*)d_in[1];
  const float* g0  = (const float*)d_in[2];
  const float* bb0 = (const float*)d_in[3];
  const float* W1  = (const float*)d_in[4];
  const float* g1  = (const float*)d_in[5];
  const float* bb1 = (const float*)d_in[6];
  const float* W2  = (const float*)d_in[7];
  const float* g2  = (const float*)d_in[8];
  const float* bb2 = (const float*)d_in[9];
  const float* W3  = (const float*)d_in[10];
  const float* g3  = (const float*)d_in[11];
  const float* bb3 = (const float*)d_in[12];
  const float* W4  = (const float*)d_in[13];
  const float* g4  = (const float*)d_in[14];
  const float* bb4 = (const float*)d_in[15];
  char* ws = (char*)d_ws;

  u64* wb0 = (u64*)(ws + OFF_WB0);
  u64* wb1 = (u64*)(ws + OFF_WB1);
  u64* wb2 = (u64*)(ws + OFF_WB2);
  u64* wb3 = (u64*)(ws + OFF_WB3);
  u64* wb4 = (u64*)(ws + OFF_WB4);

  pack_weights<<<257, 256, 0, stream>>>(W0, W1, W2, W3, W4,
                                        wb0, wb1, wb2, wb3, wb4,
                                        (int4*)(ws + OFF_SUMD));

  // One-time host-side occupancy check for the 1024-block variant.
  // Spin-barrier rule: only launch with VERIFIED margin (>=5 blocks/CU for a
  // 4/CU requirement). Otherwise use the proven 512x64 geometry (needs 2/CU,
  // capacity 3/CU verified in r14).
  static int cap1024 = -1;
  if (cap1024 < 0) {
    int nb = 0;
    const void* kptr = (const void*)fused_bnn<1024, 32>;
    if (hipOccupancyMaxActiveBlocksPerMultiprocessor(&nb, kptr, 256, 0)
        != hipSuccess) nb = 0;
    (void)hipGetLastError();
    cap1024 = nb;
  }

  if (cap1024 >= 5) {
    fused_bnn<1024, 32><<<1024, 256, 0, stream>>>(
        x, g0, g1, g2, g3, g4, bb0, bb1, bb2, bb3, bb4,
        (float*)d_out, ws);
  } else {
    fused_bnn<512, 64><<<512, 256, 0, stream>>>(
        x, g0, g1, g2, g3, g4, bb0, bb1, bb2, bb3, bb4,
        (float*)d_out, ws);
  }
}